// Round 4
// baseline (855.119 us; speedup 1.0000x reference)
//
#include <hip/hip_runtime.h>

typedef short  s16x8 __attribute__((ext_vector_type(8)));   // 8 bf16 (MFMA A/B frag)
typedef ushort u16x4 __attribute__((ext_vector_type(4)));
typedef float  f32x4 __attribute__((ext_vector_type(4)));   // MFMA C/D frag

constexpr int CIN = 32, COUT = 64, TT = 128, NN = 512;
constexpr int THREADS = 512;

__device__ __forceinline__ ushort f2bf(float f) {            // RNE float->bf16
    union { float f; unsigned u; } v; v.f = f;
    return (ushort)((v.u + 0x7FFFu + ((v.u >> 16) & 1u)) >> 16);
}
__device__ __forceinline__ float bf2f(ushort h) {
    union { unsigned u; float f; } v; v.u = ((unsigned)h) << 16; return v.f;
}

// G -> bf16 hi/lo split (hi + lo recovers ~17 mantissa bits)
__global__ void prep_gso(const float* __restrict__ g,
                         ushort* __restrict__ ghi, ushort* __restrict__ glo) {
    const int i = blockIdx.x * 256 + threadIdx.x;            // 512*512 elements
    const float v = g[i];
    const ushort hi = f2bf(v);
    ghi[i] = hi;
    glo[i] = f2bf(v - bf2f(hi));
}

// ---- swizzled LDS layouts (ushort units) ----
// _T: [32 ch][512 n]  (K=n contiguous; B-frag source for the G GEMMs)
__device__ __forceinline__ int idxT(int c, int n) {
    return c * 512 + ((((n >> 3) ^ (c & 7)) << 3) | (n & 7));
}
// _N: [512 n][32 ch]  (K=ch contiguous; A-frag source for the mix GEMM)
__device__ __forceinline__ int idxN(int n, int c) {
    return n * 32 + ((((c >> 3) ^ ((n >> 1) & 3)) << 3) | (c & 7));
}

__global__ __launch_bounds__(THREADS, 2)
void cheb_mfma(const float* __restrict__ x, const ushort* __restrict__ ghi,
               const ushort* __restrict__ glo, const float* __restrict__ wt,
               const float* __restrict__ bias, float* __restrict__ out)
{
    __shared__ ushort sXT[32 * 512];    // 32 KiB
    __shared__ ushort sYT[32 * 512];    // 32 KiB
    __shared__ ushort sXN[512 * 32];    // 32 KiB
    __shared__ ushort sYN[512 * 32];    // 32 KiB
    __shared__ ushort sW [3 * 64 * 32]; // 12 KiB   Wt_s[j][i] = W'_s[i][j] bf16
    ushort* sZN = sXT;                  // X_T dead after GEMM1 -> reuse for Z_N

    const int tid = threadIdx.x;
    const int wv  = tid >> 6;          // wave 0..7  (owns rows wv*64..wv*64+63)
    const int l   = tid & 63;
    const int lr  = l & 15;            // row (A) / col (B,D) within 16x16 tile
    const int lk  = l >> 4;            // k-chunk 0..3 (8 elems each)
    const int bt  = blockIdx.x, b = bt >> 7, t = bt & (TT - 1);

    const float* xb = x + (size_t)b * (CIN * TT * NN) + t * NN;  // xb[c*TT*NN + n]

    // per-lane global A bases (m adds 16*512 elems)
    const ushort* gh0 = ghi + (size_t)(wv * 64 + lr) * 512 + lk * 8;
    const ushort* gl0 = glo + (size_t)(wv * 64 + lr) * 512 + lk * 8;

    // ---- stage combined weights, transposed + swizzled ----
    for (int idx = tid; idx < 3 * 32 * 64; idx += THREADS) {
        const int j = idx & 63;
        const int r = idx >> 6;        // 0..95
        const int i = r & 31;
        const int s = r >> 5;          // 0..2
        const float w0 = wt[0 * 4096 + i * 64 + j];
        const float w1 = wt[1 * 4096 + i * 64 + j];
        const float w2 = wt[2 * 4096 + i * 64 + j];
        const float v  = (s == 0) ? (w0 - w2) : (s == 1) ? w1 : 2.0f * w2;
        sW[s * 2048 + j * 32 + ((((i >> 3) ^ ((j >> 1) & 3)) << 3) | (i & 7))] = f2bf(v);
    }

    // ---- stage X0: thread n loads 32 channels (coalesced), writes both layouts ----
    {
        const int n = tid;
        ushort xh[32];
        #pragma unroll
        for (int c = 0; c < 32; ++c) xh[c] = f2bf(xb[c * (TT * NN) + n]);
        #pragma unroll
        for (int c = 0; c < 32; ++c) sXT[idxT(c, n)] = xh[c];
        #pragma unroll
        for (int q = 0; q < 4; ++q) {
            s16x8 pk;
            #pragma unroll
            for (int e = 0; e < 8; ++e) pk[e] = (short)xh[q * 8 + e];
            *(s16x8*)&sXN[n * 32 + ((q ^ ((n >> 1) & 3)) << 3)] = pk;
        }
    }
    __syncthreads();

    // ---- GEMM over G (split hi/lo A, independent acc chains, depth-1 prefetch) ----
    auto run_gemm = [&](const ushort* __restrict__ Bsrc, f32x4 (&accO)[4][2]) {
        f32x4 accH[4][2], accL[4][2];
        const f32x4 zz = {0.f, 0.f, 0.f, 0.f};
        #pragma unroll
        for (int m = 0; m < 4; ++m)
            #pragma unroll
            for (int nt = 0; nt < 2; ++nt) { accH[m][nt] = zz; accL[m][nt] = zz; }

        s16x8 cah[4], cal[4], cb[2];
        #pragma unroll
        for (int m = 0; m < 4; ++m) {
            cah[m] = *(const s16x8*)(gh0 + m * 8192);
            cal[m] = *(const s16x8*)(gl0 + m * 8192);
        }
        #pragma unroll
        for (int nt = 0; nt < 2; ++nt) {
            const int c = nt * 16 + lr;
            cb[nt] = *(const s16x8*)&Bsrc[c * 512 + ((lk ^ (c & 7)) << 3)];
        }

        #pragma unroll
        for (int kk = 0; kk < 16; ++kk) {
            s16x8 nah[4], nal[4], nb[2];
            if (kk < 15) {                                  // prefetch kk+1
                const int k0n = (kk + 1) * 32;
                #pragma unroll
                for (int m = 0; m < 4; ++m) {
                    nah[m] = *(const s16x8*)(gh0 + m * 8192 + k0n);
                    nal[m] = *(const s16x8*)(gl0 + m * 8192 + k0n);
                }
                #pragma unroll
                for (int nt = 0; nt < 2; ++nt) {
                    const int c = nt * 16 + lr;
                    nb[nt] = *(const s16x8*)&Bsrc[c * 512 + ((((kk + 1) * 4 + lk) ^ (c & 7)) << 3)];
                }
            }
            #pragma unroll
            for (int m = 0; m < 4; ++m)
                #pragma unroll
                for (int nt = 0; nt < 2; ++nt) {
                    accH[m][nt] = __builtin_amdgcn_mfma_f32_16x16x32_bf16(cah[m], cb[nt], accH[m][nt], 0, 0, 0);
                    accL[m][nt] = __builtin_amdgcn_mfma_f32_16x16x32_bf16(cal[m], cb[nt], accL[m][nt], 0, 0, 0);
                }
            if (kk < 15) {
                #pragma unroll
                for (int m = 0; m < 4; ++m) { cah[m] = nah[m]; cal[m] = nal[m]; }
                cb[0] = nb[0]; cb[1] = nb[1];
            }
        }
        #pragma unroll
        for (int m = 0; m < 4; ++m)
            #pragma unroll
            for (int nt = 0; nt < 2; ++nt) accO[m][nt] = accH[m][nt] + accL[m][nt];
    };

    // ---- GEMM1: Y1 = G @ X0 ----
    {
        f32x4 a1[4][2];
        run_gemm(sXT, a1);
        // D layout: col = lr (+16*nt), rows = lk*4 + reg  (m89-verified)
        #pragma unroll
        for (int m = 0; m < 4; ++m) {
            const int h0 = wv * 64 + m * 16 + lk * 4;
            #pragma unroll
            for (int nt = 0; nt < 2; ++nt) {
                const int c = nt * 16 + lr;
                u16x4 pv;
                #pragma unroll
                for (int r = 0; r < 4; ++r) pv[r] = f2bf(a1[m][nt][r]);
                *(u16x4*)&sYT[c * 512 + ((((h0 >> 3) ^ (c & 7)) << 3) | (h0 & 7))] = pv;
                #pragma unroll
                for (int r = 0; r < 4; ++r) sYN[idxN(h0 + r, c)] = pv[r];
            }
        }
    }
    __syncthreads();

    // ---- GEMM2: Z = G @ Y1 ----
    {
        f32x4 a2[4][2];
        run_gemm(sYT, a2);
        #pragma unroll
        for (int m = 0; m < 4; ++m) {
            const int h0 = wv * 64 + m * 16 + lk * 4;
            #pragma unroll
            for (int nt = 0; nt < 2; ++nt) {
                const int c = nt * 16 + lr;
                #pragma unroll
                for (int r = 0; r < 4; ++r) sZN[idxN(h0 + r, c)] = f2bf(a2[m][nt][r]);
            }
        }
    }
    __syncthreads();

    // ---- mix GEMM: gc = [X0|Y1|Z] (512x96) @ Wcat (96x64) ----
    f32x4 mac[4][4];
    {
        const f32x4 zz = {0.f, 0.f, 0.f, 0.f};
        #pragma unroll
        for (int m = 0; m < 4; ++m)
            #pragma unroll
            for (int nt = 0; nt < 4; ++nt) mac[m][nt] = zz;
        const ushort* __restrict__ As[3] = {sXN, sYN, sZN};
        #pragma unroll
        for (int s = 0; s < 3; ++s) {
            s16x8 bw[4];
            #pragma unroll
            for (int nt = 0; nt < 4; ++nt) {
                const int j = nt * 16 + lr;
                bw[nt] = *(const s16x8*)&sW[s * 2048 + j * 32 + ((lk ^ ((j >> 1) & 3)) << 3)];
            }
            #pragma unroll
            for (int m = 0; m < 4; ++m) {
                const int n = wv * 64 + m * 16 + lr;
                const s16x8 av = *(const s16x8*)&As[s][n * 32 + ((lk ^ ((n >> 1) & 3)) << 3)];
                #pragma unroll
                for (int nt = 0; nt < 4; ++nt)
                    mac[m][nt] = __builtin_amdgcn_mfma_f32_16x16x32_bf16(av, bw[nt], mac[m][nt], 0, 0, 0);
            }
        }
    }

    // ---- epilogue: + bias + residual (fp32 from global, exact), store ----
    float* ob = out + (size_t)b * ((size_t)COUT * TT * NN) + t * NN;
    #pragma unroll
    for (int nt = 0; nt < 4; ++nt) {
        const int j = nt * 16 + lr;
        const float bj = bias[j];
        #pragma unroll
        for (int m = 0; m < 4; ++m) {
            const int n0 = wv * 64 + m * 16 + lk * 4;
            f32x4 v = mac[m][nt];
            v[0] += bj; v[1] += bj; v[2] += bj; v[3] += bj;
            if (nt < 2) {   // residual x_in for output channels j<32
                const float4 rx = *(const float4*)&xb[j * (TT * NN) + n0];
                v[0] += rx.x; v[1] += rx.y; v[2] += rx.z; v[3] += rx.w;
            }
            *(float4*)&ob[(size_t)j * (TT * NN) + n0] = make_float4(v[0], v[1], v[2], v[3]);
        }
    }
}

extern "C" void kernel_launch(void* const* d_in, const int* in_sizes, int n_in,
                              void* d_out, int out_size, void* d_ws, size_t ws_size,
                              hipStream_t stream) {
    const float* x    = (const float*)d_in[0];
    const float* gso  = (const float*)d_in[1];
    const float* wt   = (const float*)d_in[2];
    const float* bias = (const float*)d_in[3];
    float* out        = (float*)d_out;

    ushort* ghi = (ushort*)d_ws;            // 512 KiB
    ushort* glo = ghi + 512 * 512;          // 512 KiB

    prep_gso<<<dim3(1024), dim3(256), 0, stream>>>(gso, ghi, glo);
    cheb_mfma<<<dim3(16 * 128), dim3(THREADS), 0, stream>>>(x, ghi, glo, wt, bias, out);
}

// Round 6
// 572.101 us; speedup vs baseline: 1.4947x; 1.4947x over previous
//
#include <hip/hip_runtime.h>

typedef short  s16x8 __attribute__((ext_vector_type(8)));   // 8 bf16 (MFMA A/B frag)
typedef ushort u16x4 __attribute__((ext_vector_type(4)));
typedef ushort u16x8 __attribute__((ext_vector_type(8)));
typedef float  f32x4 __attribute__((ext_vector_type(4)));   // MFMA C/D frag

constexpr int CIN = 32, COUT = 64, TT = 128, NN = 512;
constexpr int THREADS = 512;

__device__ __forceinline__ ushort f2bf(float f) {            // RNE float->bf16
    union { float f; unsigned u; } v; v.f = f;
    return (ushort)((v.u + 0x7FFFu + ((v.u >> 16) & 1u)) >> 16);
}
__device__ __forceinline__ float bf2f(ushort h) {
    union { unsigned u; float f; } v; v.u = ((unsigned)h) << 16; return v.f;
}

// Pack G into MFMA A-fragment-major order, hi/lo bf16 split.
// item i = (kk*32 + rb)*64 + l ; covers G[row = rb*16 + (l&15)][k = kk*32 + (l>>4)*8 + e]
// ushort offset of fragment (kk, rb), lane l:  kk*16384 + rb*512 + l*8.
// A wave's A-frag load = 64 lanes x 16B contiguous = one 1KB burst of sequential lines.
__global__ void prep_pack(const float* __restrict__ g,
                          ushort* __restrict__ pkhi, ushort* __restrict__ pklo) {
    const int i  = blockIdx.x * 256 + threadIdx.x;      // 0..32767
    const int l  = i & 63;
    const int rb = (i >> 6) & 31;
    const int kk = i >> 11;
    const int row = rb * 16 + (l & 15);
    const int k0  = kk * 32 + (l >> 4) * 8;
    const float* src = g + row * 512 + k0;
    u16x8 h, lo;
    #pragma unroll
    for (int e = 0; e < 8; ++e) {
        const float v = src[e];
        const ushort hb = f2bf(v);
        h[e]  = hb;
        lo[e] = f2bf(v - bf2f(hb));
    }
    *(u16x8*)&pkhi[i * 8] = h;
    *(u16x8*)&pklo[i * 8] = lo;
}

// ---- swizzled LDS layouts (ushort units) ----
// _T: [32 ch][512 n]  (K=n contiguous; B-frag source for the G GEMMs)
__device__ __forceinline__ int idxT(int c, int n) {
    return c * 512 + ((((n >> 3) ^ (c & 7)) << 3) | (n & 7));
}
// _N: [512 n][32 ch]  (K=ch contiguous; A-frag source for the mix GEMM)
__device__ __forceinline__ int idxN(int n, int c) {
    return n * 32 + ((((c >> 3) ^ ((n >> 1) & 3)) << 3) | (c & 7));
}

__global__ __launch_bounds__(THREADS, 2)
void cheb_mfma(const float* __restrict__ x, const ushort* __restrict__ pkhi,
               const ushort* __restrict__ pklo, const float* __restrict__ wt,
               const float* __restrict__ bias, float* __restrict__ out)
{
    __shared__ ushort sXT[32 * 512];    // 32 KiB
    __shared__ ushort sYT[32 * 512];    // 32 KiB
    __shared__ ushort sXN[512 * 32];    // 32 KiB
    __shared__ ushort sYN[512 * 32];    // 32 KiB
    __shared__ ushort sW [3 * 64 * 32]; // 12 KiB   Wt_s[j][i] = W'_s[i][j] bf16
    ushort* sZN = sXT;                  // X_T dead after GEMM1 -> reuse for Z_N

    const int tid = threadIdx.x;
    const int wv  = tid >> 6;          // wave 0..7  (owns rows wv*64..wv*64+63)
    const int l   = tid & 63;
    const int lr  = l & 15;            // row (A) / col (B,D) within 16x16 tile
    const int lk  = l >> 4;            // k-chunk 0..3 (8 elems each)
    const int bt  = blockIdx.x, b = bt >> 7, t = bt & (TT - 1);

    const float* xb = x + (size_t)b * (CIN * TT * NN) + t * NN;  // xb[c*TT*NN + n]

    // per-lane packed-G bases (ushort units); frag (m,kk) at +m*512 + kk*16384
    const ushort* gh0 = pkhi + (size_t)(wv * 4) * 512 + l * 8;
    const ushort* gl0 = pklo + (size_t)(wv * 4) * 512 + l * 8;

    // ---- stage combined weights, transposed + swizzled ----
    for (int idx = tid; idx < 3 * 32 * 64; idx += THREADS) {
        const int j = idx & 63;
        const int r = idx >> 6;        // 0..95
        const int i = r & 31;
        const int s = r >> 5;          // 0..2
        const float w0 = wt[0 * 4096 + i * 64 + j];
        const float w1 = wt[1 * 4096 + i * 64 + j];
        const float w2 = wt[2 * 4096 + i * 64 + j];
        const float v  = (s == 0) ? (w0 - w2) : (s == 1) ? w1 : 2.0f * w2;
        sW[s * 2048 + j * 32 + ((((i >> 3) ^ ((j >> 1) & 3)) << 3) | (i & 7))] = f2bf(v);
    }

    // ---- stage X0: thread n loads 32 channels (coalesced), writes both layouts ----
    {
        const int n = tid;
        ushort xh[32];
        #pragma unroll
        for (int c = 0; c < 32; ++c) xh[c] = f2bf(xb[c * (TT * NN) + n]);
        #pragma unroll
        for (int c = 0; c < 32; ++c) sXT[idxT(c, n)] = xh[c];
        #pragma unroll
        for (int q = 0; q < 4; ++q) {
            s16x8 pk;
            #pragma unroll
            for (int e = 0; e < 8; ++e) pk[e] = (short)xh[q * 8 + e];
            *(s16x8*)&sXN[n * 32 + ((q ^ ((n >> 1) & 3)) << 3)] = pk;
        }
    }
    __syncthreads();

    // ---- GEMM over G (split hi/lo A, independent acc chains, depth-1 prefetch) ----
    auto run_gemm = [&](const ushort* __restrict__ Bsrc, f32x4 (&accO)[4][2]) {
        f32x4 accH[4][2], accL[4][2];
        const f32x4 zz = {0.f, 0.f, 0.f, 0.f};
        #pragma unroll
        for (int m = 0; m < 4; ++m)
            #pragma unroll
            for (int nt = 0; nt < 2; ++nt) { accH[m][nt] = zz; accL[m][nt] = zz; }

        s16x8 cah[4], cal[4], cb[2];
        #pragma unroll
        for (int m = 0; m < 4; ++m) {
            cah[m] = *(const s16x8*)(gh0 + m * 512);
            cal[m] = *(const s16x8*)(gl0 + m * 512);
        }
        #pragma unroll
        for (int nt = 0; nt < 2; ++nt) {
            const int c = nt * 16 + lr;
            cb[nt] = *(const s16x8*)&Bsrc[c * 512 + ((lk ^ (c & 7)) << 3)];
        }

        #pragma unroll
        for (int kk = 0; kk < 16; ++kk) {
            s16x8 nah[4], nal[4], nb[2];
            if (kk < 15) {                                  // prefetch kk+1
                const int kn = (kk + 1) * 16384;
                #pragma unroll
                for (int m = 0; m < 4; ++m) {
                    nah[m] = *(const s16x8*)(gh0 + m * 512 + kn);
                    nal[m] = *(const s16x8*)(gl0 + m * 512 + kn);
                }
                #pragma unroll
                for (int nt = 0; nt < 2; ++nt) {
                    const int c = nt * 16 + lr;
                    nb[nt] = *(const s16x8*)&Bsrc[c * 512 + ((((kk + 1) * 4 + lk) ^ (c & 7)) << 3)];
                }
            }
            #pragma unroll
            for (int m = 0; m < 4; ++m)
                #pragma unroll
                for (int nt = 0; nt < 2; ++nt) {
                    accH[m][nt] = __builtin_amdgcn_mfma_f32_16x16x32_bf16(cah[m], cb[nt], accH[m][nt], 0, 0, 0);
                    accL[m][nt] = __builtin_amdgcn_mfma_f32_16x16x32_bf16(cal[m], cb[nt], accL[m][nt], 0, 0, 0);
                }
            if (kk < 15) {
                #pragma unroll
                for (int m = 0; m < 4; ++m) { cah[m] = nah[m]; cal[m] = nal[m]; }
                cb[0] = nb[0]; cb[1] = nb[1];
            }
        }
        #pragma unroll
        for (int m = 0; m < 4; ++m)
            #pragma unroll
            for (int nt = 0; nt < 2; ++nt) accO[m][nt] = accH[m][nt] + accL[m][nt];
    };

    // ---- GEMM1: Y1 = G @ X0 ----
    {
        f32x4 a1[4][2];
        run_gemm(sXT, a1);
        // D layout: col = lr (+16*nt), rows = lk*4 + reg  (m89-verified)
        #pragma unroll
        for (int m = 0; m < 4; ++m) {
            const int h0 = wv * 64 + m * 16 + lk * 4;
            #pragma unroll
            for (int nt = 0; nt < 2; ++nt) {
                const int c = nt * 16 + lr;
                u16x4 pv;
                #pragma unroll
                for (int r = 0; r < 4; ++r) pv[r] = f2bf(a1[m][nt][r]);
                *(u16x4*)&sYT[c * 512 + ((((h0 >> 3) ^ (c & 7)) << 3) | (h0 & 7))] = pv;
                #pragma unroll
                for (int r = 0; r < 4; ++r) sYN[idxN(h0 + r, c)] = pv[r];
            }
        }
    }
    __syncthreads();

    // ---- GEMM2: Z = G @ Y1 ----
    {
        f32x4 a2[4][2];
        run_gemm(sYT, a2);
        #pragma unroll
        for (int m = 0; m < 4; ++m) {
            const int h0 = wv * 64 + m * 16 + lk * 4;
            #pragma unroll
            for (int nt = 0; nt < 2; ++nt) {
                const int c = nt * 16 + lr;
                #pragma unroll
                for (int r = 0; r < 4; ++r) sZN[idxN(h0 + r, c)] = f2bf(a2[m][nt][r]);
            }
        }
    }
    __syncthreads();

    // ---- mix GEMM: gc = [X0|Y1|Z] (512x96) @ Wcat (96x64) ----
    f32x4 mac[4][4];
    {
        const f32x4 zz = {0.f, 0.f, 0.f, 0.f};
        #pragma unroll
        for (int m = 0; m < 4; ++m)
            #pragma unroll
            for (int nt = 0; nt < 4; ++nt) mac[m][nt] = zz;
        const ushort* __restrict__ As[3] = {sXN, sYN, sZN};
        #pragma unroll
        for (int s = 0; s < 3; ++s) {
            s16x8 bw[4];
            #pragma unroll
            for (int nt = 0; nt < 4; ++nt) {
                const int j = nt * 16 + lr;
                bw[nt] = *(const s16x8*)&sW[s * 2048 + j * 32 + ((lk ^ ((j >> 1) & 3)) << 3)];
            }
            #pragma unroll
            for (int m = 0; m < 4; ++m) {
                const int n = wv * 64 + m * 16 + lr;
                const s16x8 av = *(const s16x8*)&As[s][n * 32 + ((lk ^ ((n >> 1) & 3)) << 3)];
                #pragma unroll
                for (int nt = 0; nt < 4; ++nt)
                    mac[m][nt] = __builtin_amdgcn_mfma_f32_16x16x32_bf16(av, bw[nt], mac[m][nt], 0, 0, 0);
            }
        }
    }

    // ---- epilogue: + bias + residual (fp32 from global, exact), store ----
    float* ob = out + (size_t)b * ((size_t)COUT * TT * NN) + t * NN;
    #pragma unroll
    for (int nt = 0; nt < 4; ++nt) {
        const int j = nt * 16 + lr;
        const float bj = bias[j];
        #pragma unroll
        for (int m = 0; m < 4; ++m) {
            const int n0 = wv * 64 + m * 16 + lk * 4;
            f32x4 v = mac[m][nt];
            v[0] += bj; v[1] += bj; v[2] += bj; v[3] += bj;
            if (nt < 2) {   // residual x_in for output channels j<32
                const float4 rx = *(const float4*)&xb[j * (TT * NN) + n0];
                v[0] += rx.x; v[1] += rx.y; v[2] += rx.z; v[3] += rx.w;
            }
            *(float4*)&ob[(size_t)j * (TT * NN) + n0] = make_float4(v[0], v[1], v[2], v[3]);
        }
    }
}

extern "C" void kernel_launch(void* const* d_in, const int* in_sizes, int n_in,
                              void* d_out, int out_size, void* d_ws, size_t ws_size,
                              hipStream_t stream) {
    const float* x    = (const float*)d_in[0];
    const float* gso  = (const float*)d_in[1];
    const float* wt   = (const float*)d_in[2];
    const float* bias = (const float*)d_in[3];
    float* out        = (float*)d_out;

    ushort* pkhi = (ushort*)d_ws;            // 512 KiB (fragment-major packed G hi)
    ushort* pklo = pkhi + 512 * 512;         // 512 KiB (lo)

    prep_pack<<<dim3(128), dim3(256), 0, stream>>>(gso, pkhi, pklo);
    cheb_mfma<<<dim3(16 * 128), dim3(THREADS), 0, stream>>>(x, pkhi, pklo, wt, bias, out);
}